// Round 3
// baseline (74.405 us; speedup 1.0000x reference)
//
#include <hip/hip_runtime.h>
#include <hip/hip_bf16.h>

#define N_NODES 4096
#define BATCH 8
#define FEAT 128
#define CAP 256

__device__ __forceinline__ unsigned short f2bf(float f) {
    unsigned int u = __float_as_uint(f);
    u += 0x7fffu + ((u >> 16) & 1u);   // RNE (inputs are finite, non-NaN)
    return (unsigned short)(u >> 16);
}

// acc[0..7] += p * bf16x8(hv)   (all static indices -> stays in VGPRs)
__device__ __forceinline__ void fma8(float* acc, float p, uint4 hv) {
    unsigned int u;
    u = hv.x;
    acc[0] = fmaf(p, __uint_as_float(u << 16), acc[0]);
    acc[1] = fmaf(p, __uint_as_float(u & 0xffff0000u), acc[1]);
    u = hv.y;
    acc[2] = fmaf(p, __uint_as_float(u << 16), acc[2]);
    acc[3] = fmaf(p, __uint_as_float(u & 0xffff0000u), acc[3]);
    u = hv.z;
    acc[4] = fmaf(p, __uint_as_float(u << 16), acc[4]);
    acc[5] = fmaf(p, __uint_as_float(u & 0xffff0000u), acc[5]);
    u = hv.w;
    acc[6] = fmaf(p, __uint_as_float(u << 16), acc[6]);
    acc[7] = fmaf(p, __uint_as_float(u & 0xffff0000u), acc[7]);
}

// ---------------------------------------------------------------------------
// Fused prep: blockIdx%3==0 -> GEMM role (h=x@W in bf16, + e_src/e_dst fp32);
// else -> adjacency-scan role (dense A row -> ushort neighbor list + degree).
// The two are independent; interleaving roles lets BW-heavy scan blocks and
// compute-heavy GEMM blocks co-reside on each CU.
// ---------------------------------------------------------------------------
__global__ __launch_bounds__(256) void prep(const float* __restrict__ x,
                                            const float* __restrict__ A,
                                            const float* __restrict__ W,
                                            const float* __restrict__ a_src,
                                            const float* __restrict__ a_dst,
                                            unsigned short* __restrict__ h,
                                            float* __restrict__ es,
                                            float* __restrict__ ed,
                                            unsigned short* __restrict__ nbr,
                                            int* __restrict__ deg) {
    __shared__ float Wl[FEAT * FEAT];
    int bid = blockIdx.x;
    int tid = threadIdx.x;

    if (bid % 3 == 0) {
        // ------------------- GEMM role: 64 rows per block -------------------
        int gb = bid / 3;
        {
            const float4* Wv = (const float4*)W;
            float4* Wlv = (float4*)Wl;
            for (int i = tid; i < FEAT * FEAT / 4; i += 256) Wlv[i] = Wv[i];
        }
        __syncthreads();

        int colg = tid & 15;
        int rowg = tid >> 4;
        int c0 = colg * 8;
        int m0 = gb * 64 + rowg * 4;
        const float* xr = x + (size_t)m0 * FEAT;

        float acc[4][8];
#pragma unroll
        for (int i = 0; i < 4; ++i)
#pragma unroll
            for (int c = 0; c < 8; ++c) acc[i][c] = 0.f;

        for (int k = 0; k < FEAT; k += 4) {
            float4 xv[4];
#pragma unroll
            for (int i = 0; i < 4; ++i) xv[i] = *(const float4*)(xr + i * FEAT + k);
#pragma unroll
            for (int kk = 0; kk < 4; ++kk) {
                float4 wa = *(const float4*)(&Wl[(k + kk) * FEAT + c0]);
                float4 wb = *(const float4*)(&Wl[(k + kk) * FEAT + c0 + 4]);
#pragma unroll
                for (int i = 0; i < 4; ++i) {
                    float xs = (&xv[i].x)[kk];
                    acc[i][0] += xs * wa.x; acc[i][1] += xs * wa.y;
                    acc[i][2] += xs * wa.z; acc[i][3] += xs * wa.w;
                    acc[i][4] += xs * wb.x; acc[i][5] += xs * wb.y;
                    acc[i][6] += xs * wb.z; acc[i][7] += xs * wb.w;
                }
            }
        }

        float as[8], ad[8];
#pragma unroll
        for (int c = 0; c < 8; ++c) { as[c] = a_src[c0 + c]; ad[c] = a_dst[c0 + c]; }

#pragma unroll
        for (int i = 0; i < 4; ++i) {
            uint4 pk;
            pk.x = (unsigned int)f2bf(acc[i][0]) | ((unsigned int)f2bf(acc[i][1]) << 16);
            pk.y = (unsigned int)f2bf(acc[i][2]) | ((unsigned int)f2bf(acc[i][3]) << 16);
            pk.z = (unsigned int)f2bf(acc[i][4]) | ((unsigned int)f2bf(acc[i][5]) << 16);
            pk.w = (unsigned int)f2bf(acc[i][6]) | ((unsigned int)f2bf(acc[i][7]) << 16);
            *(uint4*)(h + (size_t)(m0 + i) * FEAT + c0) = pk;

            float ps = 0.f, pd = 0.f;
#pragma unroll
            for (int c = 0; c < 8; ++c) { ps += acc[i][c] * as[c]; pd += acc[i][c] * ad[c]; }
#pragma unroll
            for (int off = 8; off >= 1; off >>= 1) {
                ps += __shfl_xor(ps, off);
                pd += __shfl_xor(pd, off);
            }
            if (colg == 0) { es[m0 + i] = ps; ed[m0 + i] = pd; }
        }
    } else {
        // ---------------- adjacency role: 4 rows per block ------------------
        int ab = (bid / 3) * 2 + (bid % 3 - 1);       // 0..1023
        int lane = tid & 63;
        int row = ab * 4 + (tid >> 6);
        const float4* ar = (const float4*)(A + (size_t)row * N_NODES);
        unsigned short* lst = nbr + (size_t)row * CAP;
        unsigned long long below = (1ull << lane) - 1ull;
        int cnt = 0;
        for (int c0 = 0; c0 < N_NODES / 4; c0 += 64) {   // 16 iterations
            float4 v = ar[c0 + lane];
            bool f0 = v.x > 0.f, f1 = v.y > 0.f, f2 = v.z > 0.f, f3 = v.w > 0.f;
            unsigned long long m0 = __ballot(f0), m1 = __ballot(f1),
                               m2 = __ballot(f2), m3 = __ballot(f3);
            int pos = cnt + (int)__popcll(m0 & below) + (int)__popcll(m1 & below)
                          + (int)__popcll(m2 & below) + (int)__popcll(m3 & below);
            int colb = 4 * (c0 + lane);
            if (f0) { if (pos < CAP) lst[pos] = (unsigned short)(colb);     ++pos; }
            if (f1) { if (pos < CAP) lst[pos] = (unsigned short)(colb + 1); ++pos; }
            if (f2) { if (pos < CAP) lst[pos] = (unsigned short)(colb + 2); ++pos; }
            if (f3) { if (pos < CAP) lst[pos] = (unsigned short)(colb + 3); ++pos; }
            cnt += (int)__popcll(m0) + (int)__popcll(m1)
                 + (int)__popcll(m2) + (int)__popcll(m3);
        }
        if (lane == 0) deg[row] = cnt < CAP ? cnt : CAP;
    }
}

// ---------------------------------------------------------------------------
// Aggregate: one wave per (b,i). Pass 1 caches z/col in registers + row max.
// Pass 2: 4 groups of 16 lanes, each group one neighbor (8 bf16 cols/lane as
// one uint4), x2 unroll = 8 neighbors/iter, two independent FMA chains.
// blockIdx&7 = batch -> XCD affinity (h[b] = 1MB, fits per-XCD 4MB L2).
// ---------------------------------------------------------------------------
__global__ __launch_bounds__(256) void aggregate(const unsigned short* __restrict__ h,
                                                 const float* __restrict__ es,
                                                 const float* __restrict__ ed,
                                                 const unsigned short* __restrict__ nbr,
                                                 const int* __restrict__ deg,
                                                 const float* __restrict__ bias,
                                                 float* __restrict__ out) {
    int lane = threadIdx.x & 63;
    int g = lane >> 4;             // neighbor slot within iteration
    int c8 = (lane & 15) * 8;      // this lane's 8 output columns
    int b = blockIdx.x & 7;
    int i = (blockIdx.x >> 3) * 4 + (threadIdx.x >> 6);

    int d = deg[i];
    const unsigned short* lst = nbr + (size_t)i * CAP;
    float esv = es[b * N_NODES + i];
    const float* edb = ed + b * N_NODES;

    // pass 1: z_j = leaky_relu(e_src[i]+e_dst[j], 0.2); row max; cache z & col
    float zv0 = -1e30f, zv1 = -1e30f, zv2 = -1e30f, zv3 = -1e30f;
    int cv0 = 0, cv1 = 0, cv2 = 0, cv3 = 0;
    float m = -1e30f;
#define PASS1(c, zz, cc)                                            \
    if (c * 64 < d) {                                               \
        int j = c * 64 + lane;                                      \
        if (j < d) {                                                \
            cc = lst[j];                                            \
            float z0 = esv + edb[cc];                               \
            zz = z0 > 0.f ? z0 : 0.2f * z0;                         \
        }                                                           \
        m = fmaxf(m, zz);                                           \
    }
    PASS1(0, zv0, cv0)
    PASS1(1, zv1, cv1)
    PASS1(2, zv2, cv2)
    PASS1(3, zv3, cv3)
#undef PASS1
#pragma unroll
    for (int off = 32; off >= 1; off >>= 1) m = fmaxf(m, __shfl_xor(m, off));

    // pass 2: p = exp(z-m); acc += p * h[b,col,:]; s = sum p
    const unsigned short* hb = h + (size_t)b * N_NODES * FEAT;
    float acc0[8], acc1[8];
#pragma unroll
    for (int k = 0; k < 8; ++k) { acc0[k] = 0.f; acc1[k] = 0.f; }
    float s = 0.f;
#define PASS2(c, zz, cc)                                                        \
    if (c * 64 < d) {                                                           \
        float p = __expf(zz - m);  /* inactive lanes: exp(-1e30-m)==0 */        \
        s += p;                                                                 \
        int n = d - c * 64; if (n > 64) n = 64;                                 \
        int nn = (n + 7) & ~7;                                                  \
        for (int jj = 0; jj < nn; jj += 8) {                                    \
            int j0 = jj + g, j1 = jj + 4 + g;                                   \
            float p0 = __shfl(p, j0); int cj0 = __shfl(cc, j0);                 \
            float p1 = __shfl(p, j1); int cj1 = __shfl(cc, j1);                 \
            uint4 h0 = *(const uint4*)(hb + (size_t)cj0 * FEAT + c8);           \
            uint4 h1 = *(const uint4*)(hb + (size_t)cj1 * FEAT + c8);           \
            fma8(acc0, p0, h0);                                                 \
            fma8(acc1, p1, h1);                                                 \
        }                                                                       \
    }
    PASS2(0, zv0, cv0)
    PASS2(1, zv1, cv1)
    PASS2(2, zv2, cv2)
    PASS2(3, zv3, cv3)
#undef PASS2

#pragma unroll
    for (int off = 32; off >= 1; off >>= 1) s += __shfl_xor(s, off);
    float inv = 1.0f / s;

    // merge chains, then the 4 neighbor-groups (same c8 across groups)
#pragma unroll
    for (int k = 0; k < 8; ++k) acc0[k] += acc1[k];
#pragma unroll
    for (int k = 0; k < 8; ++k) acc0[k] += __shfl_xor(acc0[k], 16);
#pragma unroll
    for (int k = 0; k < 8; ++k) acc0[k] += __shfl_xor(acc0[k], 32);

    if (lane < 16) {
        float4 b0 = *(const float4*)(bias + c8);
        float4 b1 = *(const float4*)(bias + c8 + 4);
        float o[8];
        o[0] = acc0[0] * inv + b0.x; o[1] = acc0[1] * inv + b0.y;
        o[2] = acc0[2] * inv + b0.z; o[3] = acc0[3] * inv + b0.w;
        o[4] = acc0[4] * inv + b1.x; o[5] = acc0[5] * inv + b1.y;
        o[6] = acc0[6] * inv + b1.z; o[7] = acc0[7] * inv + b1.w;
#pragma unroll
        for (int k = 0; k < 8; ++k) o[k] = o[k] > 0.f ? o[k] : 0.3f * o[k];
        float* orow = out + ((size_t)b * N_NODES + i) * FEAT + c8;
        *(float4*)orow = make_float4(o[0], o[1], o[2], o[3]);
        *(float4*)(orow + 4) = make_float4(o[4], o[5], o[6], o[7]);
    }
}

// ---------------------------------------------------------------------------
extern "C" void kernel_launch(void* const* d_in, const int* in_sizes, int n_in,
                              void* d_out, int out_size, void* d_ws, size_t ws_size,
                              hipStream_t stream) {
    const float* x     = (const float*)d_in[0];
    const float* A     = (const float*)d_in[1];
    const float* W     = (const float*)d_in[2];
    const float* bias  = (const float*)d_in[3];
    const float* a_src = (const float*)d_in[4];
    const float* a_dst = (const float*)d_in[5];
    float* out = (float*)d_out;

    // workspace layout (~10.7 MB total)
    char* ws = (char*)d_ws;
    unsigned short* h = (unsigned short*)ws;                  // B*N*C bf16 (8.4 MB)
    float* es = (float*)(h + (size_t)BATCH * N_NODES * FEAT); // B*N floats
    float* ed = es + BATCH * N_NODES;                         // B*N floats
    int*   dg = (int*)(ed + BATCH * N_NODES);                 // N ints
    unsigned short* nb = (unsigned short*)(dg + N_NODES);     // N*CAP ushorts (2 MB)

    hipLaunchKernelGGL(prep, dim3(1536), dim3(256), 0, stream,
                       x, A, W, a_src, a_dst, h, es, ed, nb, dg);
    hipLaunchKernelGGL(aggregate, dim3(BATCH * N_NODES / 4), dim3(256), 0, stream,
                       h, es, ed, nb, dg, bias, out);
}